// Round 3
// baseline (36.215 us; speedup 1.0000x reference)
//
#include <hip/hip_runtime.h>

// Problem constants: DIM=4096, WIDTH=4, POOL=512, BATCH=256, SEQ=16
constexpr int DIM   = 4096;
constexpr int WIDTH = 4;
constexpr int POOL  = 512;
constexpr int BATCH = 256;
constexpr int SEQ   = 16;

constexpr int HALVES     = 2;
constexpr int S_PER      = SEQ / HALVES;               // 8 outputs per thread
constexpr int D4_CHUNKS  = DIM / (4 * 256);            // 4 column-chunks per batch row
constexpr int BLK_PER_B  = D4_CHUNKS * HALVES;         // 8
constexpr int CONV_BLOCKS  = BLK_PER_B * BATCH;        // 2048
constexpr int TOTAL_BLOCKS = CONV_BLOCKS + POOL;       // 2560

__device__ __forceinline__ float4 ld4(const float* p) {
    return *reinterpret_cast<const float4*>(p);
}
__device__ __forceinline__ void st4(float* p, float4 v) {
    *reinterpret_cast<float4*>(p) = v;
}

// ---------------------------------------------------------------------------
// Fused kernel.
//   Blocks [0, CONV_BLOCKS): one (b, d-chunk, seq-half). Preload window + all
//     8 x rows into registers (11 independent loads in flight), then compute
//     conv+SiLU, store. Half 1 also writes the new state (x rows 13..15, live
//     in window registers at loop end) to out_state[idx[b]].
//   Blocks [CONV_BLOCKS, +POOL): copy conv_state row -> out_state row unless
//     the row appears in idxs (those rows are owned exclusively by half 1).
//   Write sets are disjoint => no inter-block ordering required.
// ---------------------------------------------------------------------------
__global__ __launch_bounds__(256) void fused_conv_update_kernel(
    const float* __restrict__ x,           // [BATCH, SEQ, DIM]
    const float* __restrict__ conv_state,  // [POOL, WIDTH-1, DIM]
    const float* __restrict__ weight,      // [WIDTH, DIM]
    const float* __restrict__ bias,        // [DIM]
    const int*   __restrict__ idxs,        // [BATCH]
    float*       __restrict__ out,         // [BATCH, SEQ, DIM]
    float*       __restrict__ out_state)   // [POOL, WIDTH-1, DIM]
{
    const int blk = blockIdx.x;

    if (blk < CONV_BLOCKS) {
        // ------------- conv + SiLU (+ state scatter on half 1) -------------
        const int b     = blk / BLK_PER_B;
        const int rem   = blk % BLK_PER_B;
        const int chunk = rem >> 1;
        const int half  = rem & 1;
        const int d     = (chunk * 256 + threadIdx.x) * 4;
        const int idx   = idxs[b];

        const float* xb = x + (size_t)b * SEQ * DIM + d;

        // Window init: half 0 <- conv_state rows, half 1 <- x rows 5..7.
        float4 win0, win1, win2;
        if (half == 0) {
            const float* st = conv_state + (size_t)idx * (WIDTH - 1) * DIM + d;
            win0 = ld4(st + 0 * DIM);
            win1 = ld4(st + 1 * DIM);
            win2 = ld4(st + 2 * DIM);
        } else {
            win0 = ld4(xb + (size_t)(S_PER - 3) * DIM);  // row 5
            win1 = ld4(xb + (size_t)(S_PER - 2) * DIM);  // row 6
            win2 = ld4(xb + (size_t)(S_PER - 1) * DIM);  // row 7
        }

        // Preload this half's 8 x rows (independent loads, all in flight).
        float4 xv[S_PER];
        const float* xh = xb + (size_t)half * S_PER * DIM;
#pragma unroll
        for (int i = 0; i < S_PER; ++i)
            xv[i] = ld4(xh + (size_t)i * DIM);

        // Weights + bias.
        float4 w0 = ld4(weight + 0 * DIM + d);
        float4 w1 = ld4(weight + 1 * DIM + d);
        float4 w2 = ld4(weight + 2 * DIM + d);
        float4 w3 = ld4(weight + 3 * DIM + d);
        const float4 bs = ld4(bias + d);

        float* ob = out + (size_t)b * SEQ * DIM + (size_t)half * S_PER * DIM + d;

#pragma unroll
        for (int s = 0; s < S_PER; ++s) {
            float4 acc;
            acc.x = bs.x + win0.x * w0.x + win1.x * w1.x + win2.x * w2.x + xv[s].x * w3.x;
            acc.y = bs.y + win0.y * w0.y + win1.y * w1.y + win2.y * w2.y + xv[s].y * w3.y;
            acc.z = bs.z + win0.z * w0.z + win1.z * w1.z + win2.z * w2.z + xv[s].z * w3.z;
            acc.w = bs.w + win0.w * w0.w + win1.w * w1.w + win2.w * w2.w + xv[s].w * w3.w;

            // SiLU: v / (1 + exp(-v))
            acc.x = acc.x / (1.0f + expf(-acc.x));
            acc.y = acc.y / (1.0f + expf(-acc.y));
            acc.z = acc.z / (1.0f + expf(-acc.z));
            acc.w = acc.w / (1.0f + expf(-acc.w));

            st4(ob + (size_t)s * DIM, acc);

            win0 = win1; win1 = win2; win2 = xv[s];
        }

        // Half 1 end state: win0..2 = x rows 13,14,15 = new conv state.
        if (half == 1) {
            float* sd = out_state + (size_t)idx * (WIDTH - 1) * DIM + d;
            st4(sd + 0 * DIM, win0);
            st4(sd + 1 * DIM, win1);
            st4(sd + 2 * DIM, win2);
        }
    } else {
        // ----------------- selective state-row copy -----------------
        const int row = blk - CONV_BLOCKS;

        __shared__ int skip;
        if (threadIdx.x == 0) skip = 0;
        __syncthreads();
        if (idxs[threadIdx.x] == row) skip = 1;   // BATCH == blockDim.x == 256
        __syncthreads();
        if (skip) return;

        const float4* src = reinterpret_cast<const float4*>(
            conv_state + (size_t)row * (WIDTH - 1) * DIM);
        float4* dst = reinterpret_cast<float4*>(
            out_state + (size_t)row * (WIDTH - 1) * DIM);

        constexpr int ROW_F4 = (WIDTH - 1) * DIM / 4;   // 3072 float4 per row
#pragma unroll
        for (int i = threadIdx.x; i < ROW_F4; i += 256)
            dst[i] = src[i];
    }
}

// ---------------------------------------------------------------------------
extern "C" void kernel_launch(void* const* d_in, const int* in_sizes, int n_in,
                              void* d_out, int out_size, void* d_ws, size_t ws_size,
                              hipStream_t stream)
{
    const float* x          = (const float*)d_in[0];
    const float* conv_state = (const float*)d_in[1];
    const float* weight     = (const float*)d_in[2];
    const float* bias       = (const float*)d_in[3];
    const int*   idxs       = (const int*)  d_in[4];

    float* out       = (float*)d_out;                    // [BATCH,SEQ,DIM]
    float* out_state = out + (size_t)BATCH * SEQ * DIM;  // [POOL,WIDTH-1,DIM]

    fused_conv_update_kernel<<<TOTAL_BLOCKS, 256, 0, stream>>>(
        x, conv_state, weight, bias, idxs, out, out_state);
}